// Round 8
// baseline (432.360 us; speedup 1.0000x reference)
//
#include <hip/hip_runtime.h>
#include <hip/hip_bf16.h>
#include <stdint.h>

#define F_IN 768
#define H_DIM 128
#define CAP 128   // fixed per-node CSR bucket capacity (in-deg ~Poisson(32), max ~70)

typedef __attribute__((ext_vector_type(8))) short short8;
typedef __attribute__((ext_vector_type(4))) float floatx4;

__device__ __forceinline__ unsigned short f2bf(float f) {
    union { float f; unsigned u; } v; v.f = f;
    unsigned r = v.u + 0x7fff + ((v.u >> 16) & 1);   // RNE
    return (unsigned short)(r >> 16);
}
__device__ __forceinline__ float bflo(unsigned u) {
    union { unsigned u; float f; } v; v.u = u << 16;
    return v.f;
}
__device__ __forceinline__ float bfhi(unsigned u) {
    union { unsigned u; float f; } v; v.u = u & 0xffff0000u;
    return v.f;
}

// ---------- fused: cnt zero-init + W1 -> bf16 MFMA-fragment reorder ----------
// W1B[f][kb][lane][j]: n = f*16 + (lane&15), k = kb*32 + (lane>>4)*8 + j
__global__ void k_init(int* __restrict__ cnt, int N,
                       const float* __restrict__ W1, unsigned short* __restrict__ W1B) {
    int t = blockIdx.x * blockDim.x + threadIdx.x;
    if (t < N) cnt[t] = 0;  // self loop handled implicitly in agg kernels
    if (t < 8 * 24 * 64) {
        int lane = t & 63;
        int kb = (t >> 6) % 24;
        int f  = (t >> 6) / 24;
        int r = lane & 15, quad = lane >> 4;
        int col = f * 16 + r;
        int k0 = kb * 32 + quad * 8;
        unsigned short* o = W1B + (size_t)t * 8;
#pragma unroll
        for (int j = 0; j < 8; j++) o[j] = f2bf(W1[(size_t)(k0 + j) * H_DIM + col]);
    }
}

// ---------- single-pass bucketed CSR build ----------
// De-partitioned (round-8): ONE grid-stride pass, each edge read exactly
// once (12.8 MB coalesced, vs 8x-redundant 57 MB with the old XCD-sliced
// scan). Atomics are device-scope (G12); 1.6M adds over 50k counters =
// negligible contention. Bucket slot = d*CAP + pos; pos<CAP guard makes
// overflow impossible by construction.
__global__ __launch_bounds__(256) void k_build(const int* __restrict__ ei, int E, int N,
                                               int* __restrict__ cnt, int* __restrict__ csr) {
    int stride = gridDim.x * 256;
    for (int e = blockIdx.x * 256 + threadIdx.x; e < E; e += stride) {
        int d = ei[E + e];
        d = min(max(d, 0), N - 1);
        int s = ei[e];
        s = min(max(s, 0), N - 1);
        int pos = atomicAdd(&cnt[d], 1);
        if (pos < CAP) csr[(size_t)d * CAP + pos] = s;
    }
}

// dis[i] = rsqrt(in_deg + 1)  (+1 = self loop)
__global__ void k_dis(const int* __restrict__ cnt, float* __restrict__ dis, int N) {
    int i = blockIdx.x * blockDim.x + threadIdx.x;
    if (i < N) dis[i] = rsqrtf((float)(cnt[i] + 1));
}

// ---------- GEMM1: h = bf16(x @ W1), 32 rows/block, 4 waves ----------
// 6 chunks x 128 cols, 3-deep register rotation; measured equal to the
// round-3 2-buffer version (the per-phase __syncthreads drain is the
// structural limiter at HIP level) but with half the LDS (17.9 KB).
// kb order 0..23 and all rounding unchanged -> bit-identical output.
#define CH6 128
#define S6 140

#define LOAD6(vv, c)                                                     \
    { _Pragma("unroll")                                                  \
      for (int j = 0; j < 4; j++)                                        \
          vv[j] = *(const floatx4*)(rp[j] + (c) * CH6); }

#define STORE6(b, vv)                                                    \
    { _Pragma("unroll")                                                  \
      for (int j = 0; j < 4; j++) {                                      \
          uint2 w;                                                       \
          w.x = (unsigned)f2bf(vv[j][0]) | ((unsigned)f2bf(vv[j][1]) << 16); \
          w.y = (unsigned)f2bf(vv[j][2]) | ((unsigned)f2bf(vv[j][3]) << 16); \
          *(uint2*)(&As[b][woff[j]]) = w; } }

#define MFMA6(b, c)                                                      \
    { _Pragma("unroll")                                                  \
      for (int kk = 0; kk < 4; kk++) {                                   \
          short8 af0 = *(const short8*)(&As[b][r * S6 + kk * 32 + quad * 8]);        \
          short8 af1 = *(const short8*)(&As[b][(16 + r) * S6 + kk * 32 + quad * 8]); \
          int kbg = (c) * 4 + kk;                                        \
          short8 b0 = *(const short8*)(bp + kbg * 512);                  \
          short8 b1 = *(const short8*)(bp + 12288 + kbg * 512);          \
          acc00 = __builtin_amdgcn_mfma_f32_16x16x32_bf16(af0, b0, acc00, 0, 0, 0); \
          acc01 = __builtin_amdgcn_mfma_f32_16x16x32_bf16(af0, b1, acc01, 0, 0, 0); \
          acc10 = __builtin_amdgcn_mfma_f32_16x16x32_bf16(af1, b0, acc10, 0, 0, 0); \
          acc11 = __builtin_amdgcn_mfma_f32_16x16x32_bf16(af1, b1, acc11, 0, 0, 0); } }

__global__ __launch_bounds__(256, 3) void k_gemm1(const float* __restrict__ x,
                                                  const unsigned short* __restrict__ W1B,
                                                  unsigned short* __restrict__ h, int N) {
    __shared__ unsigned short As[2][32 * S6];
    int rowblk = blockIdx.x * 32;
    int tid = threadIdx.x;
    int wv = tid >> 6;
    int lane = tid & 63;
    int quad = lane >> 4;
    int r = lane & 15;

    // staging map: seg j -> (row, 4-float granule) = ((j*256+tid)>>5, &31)
    const float* rp[4];
    int woff[4];
#pragma unroll
    for (int j = 0; j < 4; j++) {
        int idx = j * 256 + tid;
        int row = idx >> 5, c4 = idx & 31;
        int sr = min(rowblk + row, N - 1);
        rp[j] = x + (size_t)sr * F_IN + c4 * 4;
        woff[j] = row * S6 + c4 * 4;
    }

    const unsigned short* bp = W1B + ((size_t)(2 * wv) * 24 * 512) + (size_t)lane * 8;

    floatx4 acc00 = (floatx4){0.f, 0.f, 0.f, 0.f};
    floatx4 acc01 = (floatx4){0.f, 0.f, 0.f, 0.f};
    floatx4 acc10 = (floatx4){0.f, 0.f, 0.f, 0.f};
    floatx4 acc11 = (floatx4){0.f, 0.f, 0.f, 0.f};

    floatx4 v0[4], v1[4], v2[4];

    // chunk c lives in buffer c&1. 3-deep prologue:
    LOAD6(v0, 0); LOAD6(v1, 1); LOAD6(v2, 2);
    STORE6(0, v0);                    // waits vmcnt(8): v1,v2 stay in flight
    __syncthreads();

    LOAD6(v0, 3); MFMA6(0, 0); STORE6(1, v1); __syncthreads();
    LOAD6(v1, 4); MFMA6(1, 1); STORE6(0, v2); __syncthreads();
    LOAD6(v2, 5); MFMA6(0, 2); STORE6(1, v0); __syncthreads();
    MFMA6(1, 3); STORE6(0, v1); __syncthreads();
    MFMA6(0, 4); STORE6(1, v2); __syncthreads();
    MFMA6(1, 5);

    int c0 = (2 * wv) * 16 + r, c1 = (2 * wv + 1) * 16 + r;
#pragma unroll
    for (int i = 0; i < 4; i++) {
        int orow0 = rowblk + quad * 4 + i;
        int orow1 = orow0 + 16;
        if (orow0 < N) {
            h[(size_t)orow0 * H_DIM + c0] = f2bf(acc00[i]);
            h[(size_t)orow0 * H_DIM + c1] = f2bf(acc01[i]);
        }
        if (orow1 < N) {
            h[(size_t)orow1 * H_DIM + c0] = f2bf(acc10[i]);
            h[(size_t)orow1 * H_DIM + c1] = f2bf(acc11[i]);
        }
    }
}

// ---------- Aggregation layer 1 + bias + relu + @W2 fused ----------
// one wave per node; lane = 16p + c: lane holds feats 8c..8c+7 of neighbor
// slot p; 4 neighbors per inner iteration via uint4 (16B) loads.
// Self loop implicit: p==0 chain starts with dis[v]*h[v].
__global__ __launch_bounds__(256) void k_agg1(const unsigned short* __restrict__ h,
                                              const int* __restrict__ csr,
                                              const int* __restrict__ cnt,
                                              const float* __restrict__ dis,
                                              const float* __restrict__ b1,
                                              const float* __restrict__ W2,
                                              float* __restrict__ h2, int N) {
    int wv = (blockIdx.x * blockDim.x + threadIdx.x) >> 6;
    if (wv >= N) return;
    int lane = threadIdx.x & 63;
    int c = lane & 15;
    int p = lane >> 4;
    int nedge = min(cnt[wv], CAP);
    int beg = wv * CAP;
    float dv = dis[wv];

    // implicit self loop: p==0 accumulator chain starts with dv*h[wv]
    uint4 hs = *(const uint4*)(h + (size_t)wv * H_DIM + 8 * c);
    float sf = (p == 0) ? dv : 0.f;
    float a0 = sf * bflo(hs.x), a1 = sf * bfhi(hs.x);
    float a2 = sf * bflo(hs.y), a3 = sf * bfhi(hs.y);
    float a4 = sf * bflo(hs.z), a5 = sf * bfhi(hs.z);
    float a6 = sf * bflo(hs.w), a7 = sf * bfhi(hs.w);

    for (int j0 = 0; j0 < nedge; j0 += 64) {
        int idx = j0 + lane;
        bool valid = idx < nedge;
        int u = csr[valid ? (beg + idx) : beg];
        float du = valid ? dis[u] : 0.f;
        int cnt64 = nedge - j0; if (cnt64 > 64) cnt64 = 64;
        int quads = (cnt64 + 3) >> 2;
        for (int t = 0; t < quads; t++) {
            int srcl = 4 * t + p;
            int uu = __shfl(u, srcl);
            float dd = __shfl(du, srcl);
            uint4 hv = *(const uint4*)(h + (size_t)uu * H_DIM + 8 * c);
            a0 += dd * bflo(hv.x); a1 += dd * bfhi(hv.x);
            a2 += dd * bflo(hv.y); a3 += dd * bfhi(hv.y);
            a4 += dd * bflo(hv.z); a5 += dd * bfhi(hv.z);
            a6 += dd * bflo(hv.w); a7 += dd * bfhi(hv.w);
        }
    }
    // sum the 4 neighbor-slot copies (lanes c, c+16, c+32, c+48)
    a0 += __shfl_xor(a0, 16); a0 += __shfl_xor(a0, 32);
    a1 += __shfl_xor(a1, 16); a1 += __shfl_xor(a1, 32);
    a2 += __shfl_xor(a2, 16); a2 += __shfl_xor(a2, 32);
    a3 += __shfl_xor(a3, 16); a3 += __shfl_xor(a3, 32);
    a4 += __shfl_xor(a4, 16); a4 += __shfl_xor(a4, 32);
    a5 += __shfl_xor(a5, 16); a5 += __shfl_xor(a5, 32);
    a6 += __shfl_xor(a6, 16); a6 += __shfl_xor(a6, 32);
    a7 += __shfl_xor(a7, 16); a7 += __shfl_xor(a7, 32);

    floatx4 bb0 = *(const floatx4*)(b1 + 8 * c);
    floatx4 bb1 = *(const floatx4*)(b1 + 8 * c + 4);
    float h0 = fmaxf(a0 * dv + bb0[0], 0.f);
    float h1 = fmaxf(a1 * dv + bb0[1], 0.f);
    float h2a = fmaxf(a2 * dv + bb0[2], 0.f);
    float h3 = fmaxf(a3 * dv + bb0[3], 0.f);
    float h4 = fmaxf(a4 * dv + bb1[0], 0.f);
    float h5 = fmaxf(a5 * dv + bb1[1], 0.f);
    float h6 = fmaxf(a6 * dv + bb1[2], 0.f);
    float h7 = fmaxf(a7 * dv + bb1[3], 0.f);
    // W2 rows 8c..8c+7 (2 floats each)
    const float* w2p = W2 + 16 * c;
    floatx4 wA = *(const floatx4*)(w2p);
    floatx4 wB = *(const floatx4*)(w2p + 4);
    floatx4 wC = *(const floatx4*)(w2p + 8);
    floatx4 wD = *(const floatx4*)(w2p + 12);
    float p0 = h0 * wA[0] + h1 * wA[2] + h2a * wB[0] + h3 * wB[2]
             + h4 * wC[0] + h5 * wC[2] + h6 * wD[0] + h7 * wD[2];
    float p1 = h0 * wA[1] + h1 * wA[3] + h2a * wB[1] + h3 * wB[3]
             + h4 * wC[1] + h5 * wC[3] + h6 * wD[1] + h7 * wD[3];
#pragma unroll
    for (int m = 8; m >= 1; m >>= 1) {
        p0 += __shfl_xor(p0, m);
        p1 += __shfl_xor(p1, m);
    }
    if (lane == 0) {
        h2[(size_t)wv * 2]     = p0;
        h2[(size_t)wv * 2 + 1] = p1;
    }
}

// ---------- Layer-2 aggregation + bias + softmax: 16 lanes per node ----------
// Self loop implicit on lane 0 (head of its accumulation chain).
__global__ __launch_bounds__(256) void k_agg2sm(const int* __restrict__ csr,
                                                const int* __restrict__ cnt,
                                                const float* __restrict__ dis,
                                                const float* __restrict__ h2,
                                                const float* __restrict__ b2,
                                                float* __restrict__ out, int N) {
    int i = (blockIdx.x * blockDim.x + threadIdx.x) >> 4;
    if (i >= N) return;
    int l = threadIdx.x & 15;
    int nedge = min(cnt[i], CAP);
    int beg = i * CAP;
    float dv = dis[i];
    float2 hself = *(const float2*)(h2 + (size_t)i * 2);
    float sf = (l == 0) ? dv : 0.f;
    float a0 = sf * hself.x, a1 = sf * hself.y;
    for (int j = l; j < nedge; j += 16) {
        int u = csr[beg + j];
        float w = dis[u];
        float2 hv = *(const float2*)(h2 + (size_t)u * 2);
        a0 += w * hv.x;
        a1 += w * hv.y;
    }
#pragma unroll
    for (int m = 8; m >= 1; m >>= 1) {
        a0 += __shfl_xor(a0, m);
        a1 += __shfl_xor(a1, m);
    }
    if (l == 0) {
        float o0 = a0 * dv + b2[0];
        float o1 = a1 * dv + b2[1];
        float m = fmaxf(o0, o1);
        float e0 = __expf(o0 - m), e1 = __expf(o1 - m);
        float inv = 1.f / (e0 + e1);
        float2 r; r.x = e0 * inv; r.y = e1 * inv;
        *(float2*)(out + (size_t)i * 2) = r;
    }
}

extern "C" void kernel_launch(void* const* d_in, const int* in_sizes, int n_in,
                              void* d_out, int out_size, void* d_ws, size_t ws_size,
                              hipStream_t stream) {
    const float* x  = (const float*)d_in[0];
    const int*   ei = (const int*)d_in[1];
    const float* W1 = (const float*)d_in[2];
    const float* b1 = (const float*)d_in[3];
    const float* W2 = (const float*)d_in[4];
    const float* b2 = (const float*)d_in[5];
    int N = in_sizes[0] / F_IN;
    int E = in_sizes[1] / 2;

    char* p = (char*)d_ws;
    auto alloc = [&](size_t bytes) {
        void* q = (void*)p;
        p += (bytes + 255) & ~(size_t)255;
        return q;
    };
    int* cnt              = (int*)alloc((size_t)N * 4);
    int* csr              = (int*)alloc((size_t)N * CAP * 4);
    float* dis            = (float*)alloc((size_t)N * 4);
    unsigned short* W1B   = (unsigned short*)alloc((size_t)F_IN * H_DIM * 2);
    unsigned short* h     = (unsigned short*)alloc((size_t)N * H_DIM * 2);
    float* h2             = (float*)alloc((size_t)N * 2 * 4);
    float* out            = (float*)d_out;

    k_init<<<(N + 255) / 256, 256, 0, stream>>>(cnt, N, W1, W1B);
    k_build<<<4096, 256, 0, stream>>>(ei, E, N, cnt, csr);
    k_dis<<<(N + 255) / 256, 256, 0, stream>>>(cnt, dis, N);
    k_gemm1<<<(N + 31) / 32, 256, 0, stream>>>(x, W1B, h, N);
    k_agg1<<<(N + 3) / 4, 256, 0, stream>>>(h, csr, cnt, dis, b1, W2, h2, N);
    k_agg2sm<<<(N * 16 + 255) / 256, 256, 0, stream>>>(csr, cnt, dis, h2, b2, out, N);
}

// Round 9
// 398.579 us; speedup vs baseline: 1.0848x; 1.0848x over previous
//
#include <hip/hip_runtime.h>
#include <hip/hip_bf16.h>
#include <stdint.h>

#define F_IN 768
#define H_DIM 128
#define CAP 128   // fixed per-node CSR bucket capacity (in-deg ~Poisson(32), max ~70)

typedef __attribute__((ext_vector_type(8))) short short8;
typedef __attribute__((ext_vector_type(4))) float floatx4;

__device__ __forceinline__ unsigned short f2bf(float f) {
    union { float f; unsigned u; } v; v.f = f;
    unsigned r = v.u + 0x7fff + ((v.u >> 16) & 1);   // RNE
    return (unsigned short)(r >> 16);
}
__device__ __forceinline__ float bflo(unsigned u) {
    union { unsigned u; float f; } v; v.u = u << 16;
    return v.f;
}
__device__ __forceinline__ float bfhi(unsigned u) {
    union { unsigned u; float f; } v; v.u = u & 0xffff0000u;
    return v.f;
}

// ---------- fused: cnt zero-init + W1 -> bf16 MFMA-fragment reorder ----------
// W1B[f][kb][lane][j]: n = f*16 + (lane&15), k = kb*32 + (lane>>4)*8 + j
__global__ void k_init(int* __restrict__ cnt, int N,
                       const float* __restrict__ W1, unsigned short* __restrict__ W1B) {
    int t = blockIdx.x * blockDim.x + threadIdx.x;
    if (t < N) cnt[t] = 0;  // self loop handled implicitly in agg kernels
    if (t < 8 * 24 * 64) {
        int lane = t & 63;
        int kb = (t >> 6) % 24;
        int f  = (t >> 6) / 24;
        int r = lane & 15, quad = lane >> 4;
        int col = f * 16 + r;
        int k0 = kb * 32 + quad * 8;
        unsigned short* o = W1B + (size_t)t * 8;
#pragma unroll
        for (int j = 0; j < 8; j++) o[j] = f2bf(W1[(size_t)(k0 + j) * H_DIM + col]);
    }
}

// ---------- single-pass bucketed CSR build, XCD-partitioned ----------
// Round-8 lesson (measured): de-partitioned grid-stride build = 124us
// (atomic/write lines ping-pong across 8 non-coherent L2s; WRITE_SIZE 100MB).
// XCD-sliced (group g = blockIdx&7 owns dst slice g) keeps each cnt line
// and csr bucket XCD-local; the 8x redundant dst reads are cheap streaming.
__global__ __launch_bounds__(256) void k_build(const int* __restrict__ ei, int E, int N,
                                               int* __restrict__ cnt, int* __restrict__ csr) {
    int g = blockIdx.x & 7;
    int r = blockIdx.x >> 3;
    int nbg = gridDim.x >> 3;
    int span = (N + 7) >> 3;
    int lo = g * span, hi = min(lo + span, N);
    for (int e = r * 256 + threadIdx.x; e < E; e += nbg * 256) {
        int d = ei[E + e];
        d = min(max(d, 0), N - 1);
        if (d >= lo && d < hi) {
            int s = ei[e];
            s = min(max(s, 0), N - 1);
            int pos = atomicAdd(&cnt[d], 1);
            if (pos < CAP) csr[(size_t)d * CAP + pos] = s;
        }
    }
}

// dis[i] = rsqrt(in_deg + 1)  (+1 = self loop)
__global__ void k_dis(const int* __restrict__ cnt, float* __restrict__ dis, int N) {
    int i = blockIdx.x * blockDim.x + threadIdx.x;
    if (i < N) dis[i] = rsqrtf((float)(cnt[i] + 1));
}

// ---------- GEMM1: h = bf16(x @ W1), 64 rows/block, 4 waves ----------
// 6 chunks x 128 cols, depth-2 register rotation. Round-7 (32-row, depth-3)
// was neutral -> suspected compiler load-sinking (round-4 pathology). Fixes:
// (a) sched_barrier(0) after each LOAD batch pins issue-early;
// (b) 64 rows doubles per-phase compute (32 MFMA + 16 ds_read/wave) so the
//     phase covers ~900cyc HBM latency and barriers amortize over 2x work.
// LDS 2 x 64 x S6 shorts = 35.8 KB; word stride 70 % 32 = 6 (measured-good
// bank residue). kb order 0..23 unchanged -> bit-identical output.
#define CH6 128
#define S6 140

#define LOAD6(vv, c)                                                     \
    { _Pragma("unroll")                                                  \
      for (int j = 0; j < 8; j++)                                        \
          vv[j] = *(const floatx4*)(rp[j] + (c) * CH6);                  \
      __builtin_amdgcn_sched_barrier(0); }

#define STORE6(b, vv)                                                    \
    { _Pragma("unroll")                                                  \
      for (int j = 0; j < 8; j++) {                                      \
          uint2 w;                                                       \
          w.x = (unsigned)f2bf(vv[j][0]) | ((unsigned)f2bf(vv[j][1]) << 16); \
          w.y = (unsigned)f2bf(vv[j][2]) | ((unsigned)f2bf(vv[j][3]) << 16); \
          *(uint2*)(&As[b][woff[j]]) = w; } }

#define MFMA6(b, c)                                                      \
    { _Pragma("unroll")                                                  \
      for (int kk = 0; kk < 4; kk++) {                                   \
          int kbg = (c) * 4 + kk;                                        \
          short8 b0 = *(const short8*)(bp + kbg * 512);                  \
          short8 b1 = *(const short8*)(bp + 12288 + kbg * 512);          \
          _Pragma("unroll")                                              \
          for (int rt = 0; rt < 4; rt++) {                               \
              short8 af = *(const short8*)(&As[b][(rt * 16 + r) * S6 + kk * 32 + quad * 8]); \
              acc[rt][0] = __builtin_amdgcn_mfma_f32_16x16x32_bf16(af, b0, acc[rt][0], 0, 0, 0); \
              acc[rt][1] = __builtin_amdgcn_mfma_f32_16x16x32_bf16(af, b1, acc[rt][1], 0, 0, 0); \
          } } }

__global__ __launch_bounds__(256, 3) void k_gemm1(const float* __restrict__ x,
                                                  const unsigned short* __restrict__ W1B,
                                                  unsigned short* __restrict__ h, int N) {
    __shared__ unsigned short As[2][64 * S6];
    int rowblk = blockIdx.x * 64;
    int tid = threadIdx.x;
    int wv = tid >> 6;
    int lane = tid & 63;
    int quad = lane >> 4;
    int r = lane & 15;

    // staging map: seg j -> idx = j*256+tid; row = idx>>5 (0..63), c4 = idx&31
    const float* rp[8];
    int woff[8];
#pragma unroll
    for (int j = 0; j < 8; j++) {
        int idx = j * 256 + tid;
        int row = idx >> 5, c4 = idx & 31;
        int sr = min(rowblk + row, N - 1);
        rp[j] = x + (size_t)sr * F_IN + c4 * 4;
        woff[j] = row * S6 + c4 * 4;
    }

    const unsigned short* bp = W1B + ((size_t)(2 * wv) * 24 * 512) + (size_t)lane * 8;

    floatx4 acc[4][2];
#pragma unroll
    for (int rt = 0; rt < 4; rt++) {
        acc[rt][0] = (floatx4){0.f, 0.f, 0.f, 0.f};
        acc[rt][1] = (floatx4){0.f, 0.f, 0.f, 0.f};
    }

    floatx4 v0[8], v1[8];

    // depth-2 rotation: load c+2 at phase start, compute c, store c+1.
    LOAD6(v0, 0); LOAD6(v1, 1);
    STORE6(0, v0);                 // waits only v0's loads; v1 stays in flight
    __syncthreads();

    LOAD6(v0, 2); MFMA6(0, 0); STORE6(1, v1); __syncthreads();
    LOAD6(v1, 3); MFMA6(1, 1); STORE6(0, v0); __syncthreads();
    LOAD6(v0, 4); MFMA6(0, 2); STORE6(1, v1); __syncthreads();
    LOAD6(v1, 5); MFMA6(1, 3); STORE6(0, v0); __syncthreads();
    MFMA6(0, 4); STORE6(1, v1); __syncthreads();
    MFMA6(1, 5);

    int c0 = (2 * wv) * 16 + r, c1 = (2 * wv + 1) * 16 + r;
#pragma unroll
    for (int rt = 0; rt < 4; rt++) {
#pragma unroll
        for (int i = 0; i < 4; i++) {
            int orow = rowblk + rt * 16 + quad * 4 + i;
            if (orow < N) {
                h[(size_t)orow * H_DIM + c0] = f2bf(acc[rt][0][i]);
                h[(size_t)orow * H_DIM + c1] = f2bf(acc[rt][1][i]);
            }
        }
    }
}

// ---------- Aggregation layer 1 + bias + relu + @W2 fused ----------
// one wave per node; lane = 16p + c: lane holds feats 8c..8c+7 of neighbor
// slot p; 4 neighbors per inner iteration via uint4 (16B) loads.
// Self loop implicit: p==0 chain starts with dis[v]*h[v].
__global__ __launch_bounds__(256) void k_agg1(const unsigned short* __restrict__ h,
                                              const int* __restrict__ csr,
                                              const int* __restrict__ cnt,
                                              const float* __restrict__ dis,
                                              const float* __restrict__ b1,
                                              const float* __restrict__ W2,
                                              float* __restrict__ h2, int N) {
    int wv = (blockIdx.x * blockDim.x + threadIdx.x) >> 6;
    if (wv >= N) return;
    int lane = threadIdx.x & 63;
    int c = lane & 15;
    int p = lane >> 4;
    int nedge = min(cnt[wv], CAP);
    int beg = wv * CAP;
    float dv = dis[wv];

    // implicit self loop: p==0 accumulator chain starts with dv*h[wv]
    uint4 hs = *(const uint4*)(h + (size_t)wv * H_DIM + 8 * c);
    float sf = (p == 0) ? dv : 0.f;
    float a0 = sf * bflo(hs.x), a1 = sf * bfhi(hs.x);
    float a2 = sf * bflo(hs.y), a3 = sf * bfhi(hs.y);
    float a4 = sf * bflo(hs.z), a5 = sf * bfhi(hs.z);
    float a6 = sf * bflo(hs.w), a7 = sf * bfhi(hs.w);

    for (int j0 = 0; j0 < nedge; j0 += 64) {
        int idx = j0 + lane;
        bool valid = idx < nedge;
        int u = csr[valid ? (beg + idx) : beg];
        float du = valid ? dis[u] : 0.f;
        int cnt64 = nedge - j0; if (cnt64 > 64) cnt64 = 64;
        int quads = (cnt64 + 3) >> 2;
        for (int t = 0; t < quads; t++) {
            int srcl = 4 * t + p;
            int uu = __shfl(u, srcl);
            float dd = __shfl(du, srcl);
            uint4 hv = *(const uint4*)(h + (size_t)uu * H_DIM + 8 * c);
            a0 += dd * bflo(hv.x); a1 += dd * bfhi(hv.x);
            a2 += dd * bflo(hv.y); a3 += dd * bfhi(hv.y);
            a4 += dd * bflo(hv.z); a5 += dd * bfhi(hv.z);
            a6 += dd * bflo(hv.w); a7 += dd * bfhi(hv.w);
        }
    }
    // sum the 4 neighbor-slot copies (lanes c, c+16, c+32, c+48)
    a0 += __shfl_xor(a0, 16); a0 += __shfl_xor(a0, 32);
    a1 += __shfl_xor(a1, 16); a1 += __shfl_xor(a1, 32);
    a2 += __shfl_xor(a2, 16); a2 += __shfl_xor(a2, 32);
    a3 += __shfl_xor(a3, 16); a3 += __shfl_xor(a3, 32);
    a4 += __shfl_xor(a4, 16); a4 += __shfl_xor(a4, 32);
    a5 += __shfl_xor(a5, 16); a5 += __shfl_xor(a5, 32);
    a6 += __shfl_xor(a6, 16); a6 += __shfl_xor(a6, 32);
    a7 += __shfl_xor(a7, 16); a7 += __shfl_xor(a7, 32);

    floatx4 bb0 = *(const floatx4*)(b1 + 8 * c);
    floatx4 bb1 = *(const floatx4*)(b1 + 8 * c + 4);
    float h0 = fmaxf(a0 * dv + bb0[0], 0.f);
    float h1 = fmaxf(a1 * dv + bb0[1], 0.f);
    float h2a = fmaxf(a2 * dv + bb0[2], 0.f);
    float h3 = fmaxf(a3 * dv + bb0[3], 0.f);
    float h4 = fmaxf(a4 * dv + bb1[0], 0.f);
    float h5 = fmaxf(a5 * dv + bb1[1], 0.f);
    float h6 = fmaxf(a6 * dv + bb1[2], 0.f);
    float h7 = fmaxf(a7 * dv + bb1[3], 0.f);
    // W2 rows 8c..8c+7 (2 floats each)
    const float* w2p = W2 + 16 * c;
    floatx4 wA = *(const floatx4*)(w2p);
    floatx4 wB = *(const floatx4*)(w2p + 4);
    floatx4 wC = *(const floatx4*)(w2p + 8);
    floatx4 wD = *(const floatx4*)(w2p + 12);
    float p0 = h0 * wA[0] + h1 * wA[2] + h2a * wB[0] + h3 * wB[2]
             + h4 * wC[0] + h5 * wC[2] + h6 * wD[0] + h7 * wD[2];
    float p1 = h0 * wA[1] + h1 * wA[3] + h2a * wB[1] + h3 * wB[3]
             + h4 * wC[1] + h5 * wC[3] + h6 * wD[1] + h7 * wD[3];
#pragma unroll
    for (int m = 8; m >= 1; m >>= 1) {
        p0 += __shfl_xor(p0, m);
        p1 += __shfl_xor(p1, m);
    }
    if (lane == 0) {
        h2[(size_t)wv * 2]     = p0;
        h2[(size_t)wv * 2 + 1] = p1;
    }
}

// ---------- Layer-2 aggregation + bias + softmax: 16 lanes per node ----------
// Self loop implicit on lane 0 (head of its accumulation chain).
__global__ __launch_bounds__(256) void k_agg2sm(const int* __restrict__ csr,
                                                const int* __restrict__ cnt,
                                                const float* __restrict__ dis,
                                                const float* __restrict__ h2,
                                                const float* __restrict__ b2,
                                                float* __restrict__ out, int N) {
    int i = (blockIdx.x * blockDim.x + threadIdx.x) >> 4;
    if (i >= N) return;
    int l = threadIdx.x & 15;
    int nedge = min(cnt[i], CAP);
    int beg = i * CAP;
    float dv = dis[i];
    float2 hself = *(const float2*)(h2 + (size_t)i * 2);
    float sf = (l == 0) ? dv : 0.f;
    float a0 = sf * hself.x, a1 = sf * hself.y;
    for (int j = l; j < nedge; j += 16) {
        int u = csr[beg + j];
        float w = dis[u];
        float2 hv = *(const float2*)(h2 + (size_t)u * 2);
        a0 += w * hv.x;
        a1 += w * hv.y;
    }
#pragma unroll
    for (int m = 8; m >= 1; m >>= 1) {
        a0 += __shfl_xor(a0, m);
        a1 += __shfl_xor(a1, m);
    }
    if (l == 0) {
        float o0 = a0 * dv + b2[0];
        float o1 = a1 * dv + b2[1];
        float m = fmaxf(o0, o1);
        float e0 = __expf(o0 - m), e1 = __expf(o1 - m);
        float inv = 1.f / (e0 + e1);
        float2 r; r.x = e0 * inv; r.y = e1 * inv;
        *(float2*)(out + (size_t)i * 2) = r;
    }
}

extern "C" void kernel_launch(void* const* d_in, const int* in_sizes, int n_in,
                              void* d_out, int out_size, void* d_ws, size_t ws_size,
                              hipStream_t stream) {
    const float* x  = (const float*)d_in[0];
    const int*   ei = (const int*)d_in[1];
    const float* W1 = (const float*)d_in[2];
    const float* b1 = (const float*)d_in[3];
    const float* W2 = (const float*)d_in[4];
    const float* b2 = (const float*)d_in[5];
    int N = in_sizes[0] / F_IN;
    int E = in_sizes[1] / 2;

    char* p = (char*)d_ws;
    auto alloc = [&](size_t bytes) {
        void* q = (void*)p;
        p += (bytes + 255) & ~(size_t)255;
        return q;
    };
    int* cnt              = (int*)alloc((size_t)N * 4);
    int* csr              = (int*)alloc((size_t)N * CAP * 4);
    float* dis            = (float*)alloc((size_t)N * 4);
    unsigned short* W1B   = (unsigned short*)alloc((size_t)F_IN * H_DIM * 2);
    unsigned short* h     = (unsigned short*)alloc((size_t)N * H_DIM * 2);
    float* h2             = (float*)alloc((size_t)N * 2 * 4);
    float* out            = (float*)d_out;

    k_init<<<(N + 255) / 256, 256, 0, stream>>>(cnt, N, W1, W1B);
    k_build<<<2048, 256, 0, stream>>>(ei, E, N, cnt, csr);
    k_dis<<<(N + 255) / 256, 256, 0, stream>>>(cnt, dis, N);
    k_gemm1<<<(N + 63) / 64, 256, 0, stream>>>(x, W1B, h, N);
    k_agg1<<<(N + 3) / 4, 256, 0, stream>>>(h, csr, cnt, dis, b1, W2, h2, N);
    k_agg2sm<<<(N * 16 + 255) / 256, 256, 0, stream>>>(csr, cnt, dis, h2, b2, out, N);
}

// Round 10
// 389.712 us; speedup vs baseline: 1.1094x; 1.0228x over previous
//
#include <hip/hip_runtime.h>
#include <hip/hip_bf16.h>
#include <stdint.h>

#define F_IN 768
#define H_DIM 128
#define CAP 128   // fixed per-node CSR bucket capacity (in-deg ~Poisson(32), max ~70)

typedef __attribute__((ext_vector_type(8))) short short8;
typedef __attribute__((ext_vector_type(4))) float floatx4;

__device__ __forceinline__ unsigned short f2bf(float f) {
    union { float f; unsigned u; } v; v.f = f;
    unsigned r = v.u + 0x7fff + ((v.u >> 16) & 1);   // RNE
    return (unsigned short)(r >> 16);
}
__device__ __forceinline__ float bflo(unsigned u) {
    union { unsigned u; float f; } v; v.u = u << 16;
    return v.f;
}
__device__ __forceinline__ float bfhi(unsigned u) {
    union { unsigned u; float f; } v; v.u = u & 0xffff0000u;
    return v.f;
}

// ---------- fused: cnt zero-init + W1 -> bf16 MFMA-fragment reorder ----------
// W1B[f][kb][lane][j]: n = f*16 + (lane&15), k = kb*32 + (lane>>4)*8 + j
__global__ void k_init(int* __restrict__ cnt, int N,
                       const float* __restrict__ W1, unsigned short* __restrict__ W1B) {
    int t = blockIdx.x * blockDim.x + threadIdx.x;
    if (t < N) cnt[t] = 0;  // self loop handled implicitly in agg kernels
    if (t < 8 * 24 * 64) {
        int lane = t & 63;
        int kb = (t >> 6) % 24;
        int f  = (t >> 6) / 24;
        int r = lane & 15, quad = lane >> 4;
        int col = f * 16 + r;
        int k0 = kb * 32 + quad * 8;
        unsigned short* o = W1B + (size_t)t * 8;
#pragma unroll
        for (int j = 0; j < 8; j++) o[j] = f2bf(W1[(size_t)(k0 + j) * H_DIM + col]);
    }
}

// ---------- single-pass bucketed CSR build, XCD-partitioned ----------
// Round-8 lesson (measured): de-partitioned grid-stride build = 124us
// (atomic/write lines ping-pong across 8 non-coherent L2s; WRITE_SIZE 100MB).
// XCD-sliced (group g = blockIdx&7 owns dst slice g) keeps each cnt line
// and csr bucket XCD-local; the 8x redundant dst reads are cheap streaming.
__global__ __launch_bounds__(256) void k_build(const int* __restrict__ ei, int E, int N,
                                               int* __restrict__ cnt, int* __restrict__ csr) {
    int g = blockIdx.x & 7;
    int r = blockIdx.x >> 3;
    int nbg = gridDim.x >> 3;
    int span = (N + 7) >> 3;
    int lo = g * span, hi = min(lo + span, N);
    for (int e = r * 256 + threadIdx.x; e < E; e += nbg * 256) {
        int d = ei[E + e];
        d = min(max(d, 0), N - 1);
        if (d >= lo && d < hi) {
            int s = ei[e];
            s = min(max(s, 0), N - 1);
            int pos = atomicAdd(&cnt[d], 1);
            if (pos < CAP) csr[(size_t)d * CAP + pos] = s;
        }
    }
}

// dis[i] = rsqrt(in_deg + 1)  (+1 = self loop)
__global__ void k_dis(const int* __restrict__ cnt, float* __restrict__ dis, int N) {
    int i = blockIdx.x * blockDim.x + threadIdx.x;
    if (i < N) dis[i] = rsqrtf((float)(cnt[i] + 1));
}

// ---------- GEMM1: h = bf16(x @ W1), 32 rows/block, 4 waves ----------
// 6 chunks x 128 cols, depth-3 register rotation + RAW BARRIERS (T4).
// Rounds 3/5/7/9 established: every pipeline variant is neutral because
// __syncthreads() emits s_waitcnt vmcnt(0) before s_barrier, force-draining
// the prefetch queue at every phase. The barrier only NEEDS lgkmcnt(0)
// (ds_write visibility); global-load results are private registers.
// BAR() = lgkmcnt(0) + raw s_barrier + sched_barrier(0) (rule-18 fence).
// Compiler's dependence waits before STORE6 are then COUNTED vmcnt(8)
// (12 outstanding, 8 younger kept in flight) - the T4 mechanism.
// Hazards: buffers alternate read/write with >=1 barrier between
// conflicting accesses; MFMA consumes ds_reads pre-barrier via reg deps.
// kb order 0..23 and all rounding unchanged -> bit-identical output.
#define CH6 128
#define S6 140

#define BAR()                                                            \
    { asm volatile("s_waitcnt lgkmcnt(0)" ::: "memory");                 \
      __builtin_amdgcn_s_barrier();                                      \
      __builtin_amdgcn_sched_barrier(0); }

#define LOAD6(vv, c)                                                     \
    { _Pragma("unroll")                                                  \
      for (int j = 0; j < 4; j++)                                        \
          vv[j] = *(const floatx4*)(rp[j] + (c) * CH6); }

#define STORE6(b, vv)                                                    \
    { _Pragma("unroll")                                                  \
      for (int j = 0; j < 4; j++) {                                      \
          uint2 w;                                                       \
          w.x = (unsigned)f2bf(vv[j][0]) | ((unsigned)f2bf(vv[j][1]) << 16); \
          w.y = (unsigned)f2bf(vv[j][2]) | ((unsigned)f2bf(vv[j][3]) << 16); \
          *(uint2*)(&As[b][woff[j]]) = w; } }

#define MFMA6(b, c)                                                      \
    { _Pragma("unroll")                                                  \
      for (int kk = 0; kk < 4; kk++) {                                   \
          short8 af0 = *(const short8*)(&As[b][r * S6 + kk * 32 + quad * 8]);        \
          short8 af1 = *(const short8*)(&As[b][(16 + r) * S6 + kk * 32 + quad * 8]); \
          int kbg = (c) * 4 + kk;                                        \
          short8 b0 = *(const short8*)(bp + kbg * 512);                  \
          short8 b1 = *(const short8*)(bp + 12288 + kbg * 512);          \
          acc00 = __builtin_amdgcn_mfma_f32_16x16x32_bf16(af0, b0, acc00, 0, 0, 0); \
          acc01 = __builtin_amdgcn_mfma_f32_16x16x32_bf16(af0, b1, acc01, 0, 0, 0); \
          acc10 = __builtin_amdgcn_mfma_f32_16x16x32_bf16(af1, b0, acc10, 0, 0, 0); \
          acc11 = __builtin_amdgcn_mfma_f32_16x16x32_bf16(af1, b1, acc11, 0, 0, 0); } }

__global__ __launch_bounds__(256, 3) void k_gemm1(const float* __restrict__ x,
                                                  const unsigned short* __restrict__ W1B,
                                                  unsigned short* __restrict__ h, int N) {
    __shared__ unsigned short As[2][32 * S6];
    int rowblk = blockIdx.x * 32;
    int tid = threadIdx.x;
    int wv = tid >> 6;
    int lane = tid & 63;
    int quad = lane >> 4;
    int r = lane & 15;

    // staging map: seg j -> (row, 4-float granule) = ((j*256+tid)>>5, &31)
    const float* rp[4];
    int woff[4];
#pragma unroll
    for (int j = 0; j < 4; j++) {
        int idx = j * 256 + tid;
        int row = idx >> 5, c4 = idx & 31;
        int sr = min(rowblk + row, N - 1);
        rp[j] = x + (size_t)sr * F_IN + c4 * 4;
        woff[j] = row * S6 + c4 * 4;
    }

    const unsigned short* bp = W1B + ((size_t)(2 * wv) * 24 * 512) + (size_t)lane * 8;

    floatx4 acc00 = (floatx4){0.f, 0.f, 0.f, 0.f};
    floatx4 acc01 = (floatx4){0.f, 0.f, 0.f, 0.f};
    floatx4 acc10 = (floatx4){0.f, 0.f, 0.f, 0.f};
    floatx4 acc11 = (floatx4){0.f, 0.f, 0.f, 0.f};

    floatx4 v0[4], v1[4], v2[4];

    // chunk c lives in buffer c&1. 3-deep prologue:
    LOAD6(v0, 0); LOAD6(v1, 1); LOAD6(v2, 2);
    STORE6(0, v0);                    // waits vmcnt(8): v1,v2 stay in flight
    BAR();

    LOAD6(v0, 3); MFMA6(0, 0); STORE6(1, v1); BAR();
    LOAD6(v1, 4); MFMA6(1, 1); STORE6(0, v2); BAR();
    LOAD6(v2, 5); MFMA6(0, 2); STORE6(1, v0); BAR();
    MFMA6(1, 3); STORE6(0, v1); BAR();
    MFMA6(0, 4); STORE6(1, v2); BAR();
    MFMA6(1, 5);

    int c0 = (2 * wv) * 16 + r, c1 = (2 * wv + 1) * 16 + r;
#pragma unroll
    for (int i = 0; i < 4; i++) {
        int orow0 = rowblk + quad * 4 + i;
        int orow1 = orow0 + 16;
        if (orow0 < N) {
            h[(size_t)orow0 * H_DIM + c0] = f2bf(acc00[i]);
            h[(size_t)orow0 * H_DIM + c1] = f2bf(acc01[i]);
        }
        if (orow1 < N) {
            h[(size_t)orow1 * H_DIM + c0] = f2bf(acc10[i]);
            h[(size_t)orow1 * H_DIM + c1] = f2bf(acc11[i]);
        }
    }
}

// ---------- Aggregation layer 1 + bias + relu + @W2 fused ----------
// one wave per node; lane = 16p + c: lane holds feats 8c..8c+7 of neighbor
// slot p; 4 neighbors per inner iteration via uint4 (16B) loads.
// Self loop implicit: p==0 chain starts with dis[v]*h[v].
__global__ __launch_bounds__(256) void k_agg1(const unsigned short* __restrict__ h,
                                              const int* __restrict__ csr,
                                              const int* __restrict__ cnt,
                                              const float* __restrict__ dis,
                                              const float* __restrict__ b1,
                                              const float* __restrict__ W2,
                                              float* __restrict__ h2, int N) {
    int wv = (blockIdx.x * blockDim.x + threadIdx.x) >> 6;
    if (wv >= N) return;
    int lane = threadIdx.x & 63;
    int c = lane & 15;
    int p = lane >> 4;
    int nedge = min(cnt[wv], CAP);
    int beg = wv * CAP;
    float dv = dis[wv];

    // implicit self loop: p==0 accumulator chain starts with dv*h[wv]
    uint4 hs = *(const uint4*)(h + (size_t)wv * H_DIM + 8 * c);
    float sf = (p == 0) ? dv : 0.f;
    float a0 = sf * bflo(hs.x), a1 = sf * bfhi(hs.x);
    float a2 = sf * bflo(hs.y), a3 = sf * bfhi(hs.y);
    float a4 = sf * bflo(hs.z), a5 = sf * bfhi(hs.z);
    float a6 = sf * bflo(hs.w), a7 = sf * bfhi(hs.w);

    for (int j0 = 0; j0 < nedge; j0 += 64) {
        int idx = j0 + lane;
        bool valid = idx < nedge;
        int u = csr[valid ? (beg + idx) : beg];
        float du = valid ? dis[u] : 0.f;
        int cnt64 = nedge - j0; if (cnt64 > 64) cnt64 = 64;
        int quads = (cnt64 + 3) >> 2;
        for (int t = 0; t < quads; t++) {
            int srcl = 4 * t + p;
            int uu = __shfl(u, srcl);
            float dd = __shfl(du, srcl);
            uint4 hv = *(const uint4*)(h + (size_t)uu * H_DIM + 8 * c);
            a0 += dd * bflo(hv.x); a1 += dd * bfhi(hv.x);
            a2 += dd * bflo(hv.y); a3 += dd * bfhi(hv.y);
            a4 += dd * bflo(hv.z); a5 += dd * bfhi(hv.z);
            a6 += dd * bflo(hv.w); a7 += dd * bfhi(hv.w);
        }
    }
    // sum the 4 neighbor-slot copies (lanes c, c+16, c+32, c+48)
    a0 += __shfl_xor(a0, 16); a0 += __shfl_xor(a0, 32);
    a1 += __shfl_xor(a1, 16); a1 += __shfl_xor(a1, 32);
    a2 += __shfl_xor(a2, 16); a2 += __shfl_xor(a2, 32);
    a3 += __shfl_xor(a3, 16); a3 += __shfl_xor(a3, 32);
    a4 += __shfl_xor(a4, 16); a4 += __shfl_xor(a4, 32);
    a5 += __shfl_xor(a5, 16); a5 += __shfl_xor(a5, 32);
    a6 += __shfl_xor(a6, 16); a6 += __shfl_xor(a6, 32);
    a7 += __shfl_xor(a7, 16); a7 += __shfl_xor(a7, 32);

    floatx4 bb0 = *(const floatx4*)(b1 + 8 * c);
    floatx4 bb1 = *(const floatx4*)(b1 + 8 * c + 4);
    float h0 = fmaxf(a0 * dv + bb0[0], 0.f);
    float h1 = fmaxf(a1 * dv + bb0[1], 0.f);
    float h2a = fmaxf(a2 * dv + bb0[2], 0.f);
    float h3 = fmaxf(a3 * dv + bb0[3], 0.f);
    float h4 = fmaxf(a4 * dv + bb1[0], 0.f);
    float h5 = fmaxf(a5 * dv + bb1[1], 0.f);
    float h6 = fmaxf(a6 * dv + bb1[2], 0.f);
    float h7 = fmaxf(a7 * dv + bb1[3], 0.f);
    // W2 rows 8c..8c+7 (2 floats each)
    const float* w2p = W2 + 16 * c;
    floatx4 wA = *(const floatx4*)(w2p);
    floatx4 wB = *(const floatx4*)(w2p + 4);
    floatx4 wC = *(const floatx4*)(w2p + 8);
    floatx4 wD = *(const floatx4*)(w2p + 12);
    float p0 = h0 * wA[0] + h1 * wA[2] + h2a * wB[0] + h3 * wB[2]
             + h4 * wC[0] + h5 * wC[2] + h6 * wD[0] + h7 * wD[2];
    float p1 = h0 * wA[1] + h1 * wA[3] + h2a * wB[1] + h3 * wB[3]
             + h4 * wC[1] + h5 * wC[3] + h6 * wD[1] + h7 * wD[3];
#pragma unroll
    for (int m = 8; m >= 1; m >>= 1) {
        p0 += __shfl_xor(p0, m);
        p1 += __shfl_xor(p1, m);
    }
    if (lane == 0) {
        h2[(size_t)wv * 2]     = p0;
        h2[(size_t)wv * 2 + 1] = p1;
    }
}

// ---------- Layer-2 aggregation + bias + softmax: 16 lanes per node ----------
// Self loop implicit on lane 0 (head of its accumulation chain).
__global__ __launch_bounds__(256) void k_agg2sm(const int* __restrict__ csr,
                                                const int* __restrict__ cnt,
                                                const float* __restrict__ dis,
                                                const float* __restrict__ h2,
                                                const float* __restrict__ b2,
                                                float* __restrict__ out, int N) {
    int i = (blockIdx.x * blockDim.x + threadIdx.x) >> 4;
    if (i >= N) return;
    int l = threadIdx.x & 15;
    int nedge = min(cnt[i], CAP);
    int beg = i * CAP;
    float dv = dis[i];
    float2 hself = *(const float2*)(h2 + (size_t)i * 2);
    float sf = (l == 0) ? dv : 0.f;
    float a0 = sf * hself.x, a1 = sf * hself.y;
    for (int j = l; j < nedge; j += 16) {
        int u = csr[beg + j];
        float w = dis[u];
        float2 hv = *(const float2*)(h2 + (size_t)u * 2);
        a0 += w * hv.x;
        a1 += w * hv.y;
    }
#pragma unroll
    for (int m = 8; m >= 1; m >>= 1) {
        a0 += __shfl_xor(a0, m);
        a1 += __shfl_xor(a1, m);
    }
    if (l == 0) {
        float o0 = a0 * dv + b2[0];
        float o1 = a1 * dv + b2[1];
        float m = fmaxf(o0, o1);
        float e0 = __expf(o0 - m), e1 = __expf(o1 - m);
        float inv = 1.f / (e0 + e1);
        float2 r; r.x = e0 * inv; r.y = e1 * inv;
        *(float2*)(out + (size_t)i * 2) = r;
    }
}

extern "C" void kernel_launch(void* const* d_in, const int* in_sizes, int n_in,
                              void* d_out, int out_size, void* d_ws, size_t ws_size,
                              hipStream_t stream) {
    const float* x  = (const float*)d_in[0];
    const int*   ei = (const int*)d_in[1];
    const float* W1 = (const float*)d_in[2];
    const float* b1 = (const float*)d_in[3];
    const float* W2 = (const float*)d_in[4];
    const float* b2 = (const float*)d_in[5];
    int N = in_sizes[0] / F_IN;
    int E = in_sizes[1] / 2;

    char* p = (char*)d_ws;
    auto alloc = [&](size_t bytes) {
        void* q = (void*)p;
        p += (bytes + 255) & ~(size_t)255;
        return q;
    };
    int* cnt              = (int*)alloc((size_t)N * 4);
    int* csr              = (int*)alloc((size_t)N * CAP * 4);
    float* dis            = (float*)alloc((size_t)N * 4);
    unsigned short* W1B   = (unsigned short*)alloc((size_t)F_IN * H_DIM * 2);
    unsigned short* h     = (unsigned short*)alloc((size_t)N * H_DIM * 2);
    float* h2             = (float*)alloc((size_t)N * 2 * 4);
    float* out            = (float*)d_out;

    k_init<<<(N + 255) / 256, 256, 0, stream>>>(cnt, N, W1, W1B);
    k_build<<<2048, 256, 0, stream>>>(ei, E, N, cnt, csr);
    k_dis<<<(N + 255) / 256, 256, 0, stream>>>(cnt, dis, N);
    k_gemm1<<<(N + 31) / 32, 256, 0, stream>>>(x, W1B, h, N);
    k_agg1<<<(N + 3) / 4, 256, 0, stream>>>(h, csr, cnt, dis, b1, W2, h2, N);
    k_agg2sm<<<(N * 16 + 255) / 256, 256, 0, stream>>>(csr, cnt, dis, h2, b2, out, N);
}